// Round 7
// baseline (374.818 us; speedup 1.0000x reference)
//
#include <hip/hip_runtime.h>
#include <math.h>

#define B_DIM 16
#define A_DIM 1024
#define V_DIM 512
#define D_DIM 512
#define NEGV  (-1e30f)
#define SKT_W 768   // skewT columns: pc = c + off(i), off in [0,255], c in [0,512)

typedef short bf16x8 __attribute__((ext_vector_type(8)));
typedef float floatx4 __attribute__((ext_vector_type(4)));

// round-to-nearest-even fp32 -> bf16
__device__ __forceinline__ short bf16_rne(float f) {
    unsigned u = __float_as_uint(f);
    return (short)((u + 0x7fffu + ((u >> 16) & 1u)) >> 16);
}

__device__ __forceinline__ float max3f(float a, float b, float c) {
    float d;
    asm("v_max3_f32 %0, %1, %2, %3" : "=v"(d) : "v"(a), "v"(b), "v"(c));
    return d;
}

// ---------------------------------------------------------------------------
// Merged elementwise fp32 -> bf16 for three segments (8 elems/thread).
// ---------------------------------------------------------------------------
__global__ __launch_bounds__(256) void cvt3_bf16_kernel(
    const float* __restrict__ in0, unsigned short* __restrict__ out0, int nb0,
    const float* __restrict__ in1, unsigned short* __restrict__ out1, int nb1,
    const float* __restrict__ in2, unsigned short* __restrict__ out2)
{
    int blk = blockIdx.x;
    const float* in; unsigned short* out;
    if (blk < nb0)              { in = in0; out = out0; }
    else if (blk < nb0 + nb1)   { in = in1; out = out1; blk -= nb0; }
    else                        { in = in2; out = out2; blk -= nb0 + nb1; }
    const int i = blk * 256 + threadIdx.x;
    float4 u = ((const float4*)in)[2*i];
    float4 v = ((const float4*)in)[2*i + 1];
    bf16x8 h;
    h[0]=bf16_rne(u.x); h[1]=bf16_rne(u.y); h[2]=bf16_rne(u.z); h[3]=bf16_rne(u.w);
    h[4]=bf16_rne(v.x); h[5]=bf16_rne(v.y); h[6]=bf16_rne(v.z); h[7]=bf16_rne(v.w);
    *(bf16x8*)(out + (size_t)i * 8) = h;
}

// ---------------------------------------------------------------------------
// bf16 MFMA NT GEMM with register-prefetch K-pipeline. 128x128 tile, BK=32.
// ---------------------------------------------------------------------------
__global__ __launch_bounds__(256) void gemm_bf16_nt(
    const unsigned short* __restrict__ Ag, const unsigned short* __restrict__ Bg,
    const float* __restrict__ bias, float* __restrict__ Cg,
    int M, int N, int K, size_t strA, size_t strB, size_t strC)
{
    __shared__ __align__(16) unsigned short lA[8*64*8];   // 8 KB
    __shared__ __align__(16) unsigned short lB[8*64*8];

    const unsigned short* Ab = Ag + (size_t)blockIdx.z * strA;
    const unsigned short* Bb = Bg + (size_t)blockIdx.z * strB;
    float*                Cb = Cg + (size_t)blockIdx.z * strC;

    const int m0 = blockIdx.y * 128;
    const int n0 = blockIdx.x * 128;
    const int tid = threadIdx.x, lane = tid & 63;
    const int w = tid >> 6, wy = w >> 1, wx = w & 1;

    const int u0 = tid, u1 = tid + 256;
    const int r_u0 = ((u0 >> 6) << 4) + (u0 & 15), k_u0 = ((u0 >> 4) & 3) * 8;
    const int r_u1 = ((u1 >> 6) << 4) + (u1 & 15), k_u1 = ((u1 >> 4) & 3) * 8;

    const unsigned short* gA0 = Ab + (size_t)(m0 + r_u0) * K + k_u0;
    const unsigned short* gA1 = Ab + (size_t)(m0 + r_u1) * K + k_u1;
    const unsigned short* gB0 = Bb + (size_t)(n0 + r_u0) * K + k_u0;
    const unsigned short* gB1 = Bb + (size_t)(n0 + r_u1) * K + k_u1;

    floatx4 acc[4][4];
    #pragma unroll
    for (int i = 0; i < 4; ++i)
        #pragma unroll
        for (int j = 0; j < 4; ++j) acc[i][j] = (floatx4){0.f, 0.f, 0.f, 0.f};

    bf16x8 a0 = *(const bf16x8*)(gA0);
    bf16x8 a1 = *(const bf16x8*)(gA1);
    bf16x8 b0 = *(const bf16x8*)(gB0);
    bf16x8 b1 = *(const bf16x8*)(gB1);

    for (int k0 = 0; k0 < K; k0 += 32) {
        __syncthreads();
        *(bf16x8*)&lA[(size_t)u0 * 8] = a0;
        *(bf16x8*)&lA[(size_t)u1 * 8] = a1;
        *(bf16x8*)&lB[(size_t)u0 * 8] = b0;
        *(bf16x8*)&lB[(size_t)u1 * 8] = b1;
        __syncthreads();

        if (k0 + 32 < K) {
            a0 = *(const bf16x8*)(gA0 + k0 + 32);
            a1 = *(const bf16x8*)(gA1 + k0 + 32);
            b0 = *(const bf16x8*)(gB0 + k0 + 32);
            b1 = *(const bf16x8*)(gB1 + k0 + 32);
        }

        bf16x8 fa[4], fb[4];
        #pragma unroll
        for (int t = 0; t < 4; ++t) {
            fa[t] = *(const bf16x8*)&lA[(((wy*4 + t)*64) + lane) * 8];
            fb[t] = *(const bf16x8*)&lB[(((wx*4 + t)*64) + lane) * 8];
        }
        #pragma unroll
        for (int i = 0; i < 4; ++i)
            #pragma unroll
            for (int j = 0; j < 4; ++j)
                acc[i][j] = __builtin_amdgcn_mfma_f32_16x16x32_bf16(fa[i], fb[j], acc[i][j], 0, 0, 0);
    }

    const int q = lane >> 4, c = lane & 15;
    #pragma unroll
    for (int i = 0; i < 4; ++i)
        #pragma unroll
        for (int j = 0; j < 4; ++j) {
            const int n = n0 + (wx*4 + j)*16 + c;
            const float bv = bias ? bias[n] : 0.f;
            #pragma unroll
            for (int r = 0; r < 4; ++r) {
                const int m = m0 + (wy*4 + i)*16 + q*4 + r;
                Cb[(size_t)m * N + n] = acc[i][j][r] + bv;
            }
        }
}

// ---------------------------------------------------------------------------
// Row L2-normalize fp32 -> bf16. One wave/row (512 cols).
// ---------------------------------------------------------------------------
__global__ __launch_bounds__(256) void rownorm_cvt_kernel(
    const float* __restrict__ in, unsigned short* __restrict__ out)
{
    const int wave = threadIdx.x >> 6;
    const int lane = threadIdx.x & 63;
    const size_t r = (size_t)blockIdx.x * 4 + wave;
    const float* p = in + r * D_DIM + lane * 8;
    float4 u = *(const float4*)p;
    float4 w = *(const float4*)(p + 4);
    float ss = u.x*u.x + u.y*u.y + u.z*u.z + u.w*u.w
             + w.x*w.x + w.y*w.y + w.z*w.z + w.w*w.w;
    #pragma unroll
    for (int m = 1; m < 64; m <<= 1) ss += __shfl_xor(ss, m, 64);
    const float inv = 1.0f / fmaxf(sqrtf(ss), 1e-12f);
    bf16x8 h;
    h[0]=bf16_rne(u.x*inv); h[1]=bf16_rne(u.y*inv); h[2]=bf16_rne(u.z*inv); h[3]=bf16_rne(u.w*inv);
    h[4]=bf16_rne(w.x*inv); h[5]=bf16_rne(w.y*inv); h[6]=bf16_rne(w.z*inv); h[7]=bf16_rne(w.w*inv);
    *(bf16x8*)(out + r * D_DIM + lane * 8) = h;
}

// ---------------------------------------------------------------------------
// DPP helper (wave64). 0x138 = wave_shr:1 (lane l <- l-1; lane 0 keeps oldv
// with bound_ctrl=false). Verified in prior rounds.
// ---------------------------------------------------------------------------
template <int CTRL, int RMASK>
__device__ __forceinline__ float fdpp(float oldv, float src) {
    int r = __builtin_amdgcn_update_dpp(
        __float_as_int(oldv), __float_as_int(src), CTRL, RMASK, 0xF, false);
    return __int_as_float(r);
}

// ---------------------------------------------------------------------------
// Fused: row softmax -> Pbf (bf16) + TRANSPOSED skewed fp32 copy of the raw
// sim row: skewT[b][c + off(i)][i] = sim[b][i][c].
// DTW mapping: lane l, group q owns rows 256q+4l..+3, off(i) =
// ((i&255)>>2) + 64*(i>>8). A block's 4 rows are one quad -> same off, so
// each output chunk skewT[pc][i0..i0+3] is a contiguous 16B run (via LDS
// transpose). Garbage columns (pc outside [off, off+512)) are never read:
// the DTW predicates those cells off.
// ---------------------------------------------------------------------------
__global__ __launch_bounds__(256) void softmax_skewT_kernel(
    const float* __restrict__ sim, unsigned short* __restrict__ Pbf,
    float* __restrict__ skewT)
{
    __shared__ float tl[4][520];
    const int wave = threadIdx.x >> 6;
    const int lane = threadIdx.x & 63;
    const size_t r = (size_t)blockIdx.x * 4 + wave;
    const float* p = sim + r * V_DIM + lane * 8;
    float4 u = *(const float4*)p;
    float4 w = *(const float4*)(p + 4);
    float s[8] = {u.x,u.y,u.z,u.w,w.x,w.y,w.z,w.w};

    float m = s[0];
    #pragma unroll
    for (int k = 1; k < 8; ++k) m = fmaxf(m, s[k]);
    #pragma unroll
    for (int t = 1; t < 64; t <<= 1) m = fmaxf(m, __shfl_xor(m, t, 64));

    const float L2E = 1.44269504f;
    float ex[8];
    float e = 0.f;
    #pragma unroll
    for (int k = 0; k < 8; ++k) { ex[k] = exp2f((s[k] - m) * L2E); e += ex[k]; }
    #pragma unroll
    for (int t = 1; t < 64; t <<= 1) e += __shfl_xor(e, t, 64);
    const float ri = 1.0f / e;

    bf16x8 h;
    #pragma unroll
    for (int k = 0; k < 8; ++k) h[k] = bf16_rne(ex[k] * ri);
    *(bf16x8*)(Pbf + r * V_DIM + lane * 8) = h;

    // stash raw sim row in LDS, then write transposed 16B runs
    #pragma unroll
    for (int k = 0; k < 8; ++k) tl[wave][lane * 8 + k] = s[k];
    __syncthreads();

    const int r0 = blockIdx.x * 4;
    const int b  = r0 >> 10;
    const int i0 = r0 & 1023;
    const int off = ((i0 & 255) >> 2) + 64 * (i0 >> 8);
    float* base = skewT + ((size_t)b * SKT_W + off) * 1024 + i0;
    #pragma unroll
    for (int cc = 0; cc < 2; ++cc) {
        const int c = threadIdx.x + cc * 256;
        float4 v = make_float4(tl[0][c], tl[1][c], tl[2][c], tl[3][c]);
        *(float4*)(base + (size_t)c * 1024) = v;
    }
}

// ---------------------------------------------------------------------------
// Batched 32x32 transpose + cvt: video[b][v][d] fp32 -> vT[b][d][v] bf16.
// ---------------------------------------------------------------------------
__global__ __launch_bounds__(256) void transpose_cvt_kernel(
    const float* __restrict__ in, unsigned short* __restrict__ out)
{
    __shared__ float t[32][33];
    const int b = blockIdx.z;
    const int v0 = blockIdx.y * 32, d0 = blockIdx.x * 32;
    const int x = threadIdx.x & 31, y0 = (threadIdx.x >> 5) * 4;
    const float* I = in + ((size_t)b * V_DIM + v0) * D_DIM + d0;
    #pragma unroll
    for (int r = 0; r < 4; ++r) t[y0 + r][x] = I[(size_t)(y0 + r) * D_DIM + x];
    __syncthreads();
    unsigned short* O = out + ((size_t)b * D_DIM + d0) * V_DIM + v0;
    #pragma unroll
    for (int r = 0; r < 4; ++r) O[(size_t)(y0 + r) * V_DIM + x] = (unsigned short)bf16_rne(t[x][y0 + r]);
}

// ---------------------------------------------------------------------------
// Fused PV GEMM + 1-wave staggered DTW with COALESCED column loads.
// DTW (blocks 0..15, one wave, no barriers/LDS): lane l, group q owns rows
// 256q+4l..+3; off = l + 64q. Step t: group q computes its column t-off from
// skewT column t (contiguous 4KB; load instr q = 64 lanes x consecutive 16B
// -> 16 cache lines, coalesced). Guarded cell updates + unconditional chain
// updates = R5-verified predication semantics; cell math = R6-verified chain.
// Lane63->lane0 group boundary handoff via readlane + DPP fill.
// ---------------------------------------------------------------------------
__global__ __launch_bounds__(256) void pv_dtw_kernel(
    const unsigned short* __restrict__ Pbf, const unsigned short* __restrict__ vTb,
    const float* __restrict__ skewT, float* __restrict__ out_aligned,
    float* __restrict__ out_score)
{
    __shared__ __align__(16) unsigned short lA[8*64*8];
    __shared__ __align__(16) unsigned short lB[8*64*8];

    if (blockIdx.x < 16) {
        // ---------------- DTW path (one wave) ----------------
        if (threadIdx.x >= 64) return;
        const int b    = blockIdx.x;
        const int lane = threadIdx.x;
        const float* Sb = skewT + (size_t)b * SKT_W * 1024;

        float dp00=NEGV, dp01=NEGV, dp02=NEGV, dp03=NEGV;
        float dp10=NEGV, dp11=NEGV, dp12=NEGV, dp13=NEGV;
        float dp20=NEGV, dp21=NEGV, dp22=NEGV, dp23=NEGV;
        float dp30=NEGV, dp31=NEGV, dp32=NEGV, dp33=NEGV;
        float uc0=NEGV, uc1=NEGV, uc2=NEGV, uc3=NEGV;
        float uo1=NEGV, uo2=NEGV, uo3=NEGV;
        float uo0 = (lane == 0) ? 0.0f : NEGV;   // diag for cell (0,0)
        int jj0 = -lane;                          // = t - lane (group-0 column)

        float4 C0[4], C1[4], C2[4], C3[4];
#define RELOAD(BUF, COL)                                                      \
        {                                                                     \
            int c_ = (COL); if (c_ > 767) c_ = 767;                           \
            const float* cp_ = Sb + (size_t)c_ * 1024 + 4 * lane;             \
            BUF[0] = *(const float4*)(cp_);                                   \
            BUF[1] = *(const float4*)(cp_ + 256);                             \
            BUF[2] = *(const float4*)(cp_ + 512);                             \
            BUF[3] = *(const float4*)(cp_ + 768);                             \
        }
        RELOAD(C0, 0) RELOAD(C1, 1) RELOAD(C2, 2) RELOAD(C3, 3)

#define CELL(CVAL, DP) { float o_ = DP; float n_ = (CVAL) + max3f(u, DP, g); DP = n_; g = o_; u = n_; }

#define DTW_STEP(BUF)                                                         \
        {                                                                     \
            float u, g, n0v, n1v, n2v, n3v;                                   \
            u = uc0; g = uo0;                                                 \
            if ((unsigned)jj0 < 512u) {                                       \
                CELL(BUF[0].x, dp00) CELL(BUF[0].y, dp01)                     \
                CELL(BUF[0].z, dp02) CELL(BUF[0].w, dp03)                     \
            }                                                                 \
            n0v = dp03;                                                       \
            u = uc1; g = uo1;                                                 \
            if ((unsigned)(jj0 - 64) < 512u) {                                \
                CELL(BUF[1].x, dp10) CELL(BUF[1].y, dp11)                     \
                CELL(BUF[1].z, dp12) CELL(BUF[1].w, dp13)                     \
            }                                                                 \
            n1v = dp13;                                                       \
            u = uc2; g = uo2;                                                 \
            if ((unsigned)(jj0 - 128) < 512u) {                               \
                CELL(BUF[2].x, dp20) CELL(BUF[2].y, dp21)                     \
                CELL(BUF[2].z, dp22) CELL(BUF[2].w, dp23)                     \
            }                                                                 \
            n2v = dp23;                                                       \
            u = uc3; g = uo3;                                                 \
            if ((unsigned)(jj0 - 192) < 512u) {                               \
                CELL(BUF[3].x, dp30) CELL(BUF[3].y, dp31)                     \
                CELL(BUF[3].z, dp32) CELL(BUF[3].w, dp33)                     \
            }                                                                 \
            n3v = dp33;                                                       \
            float f1 = __int_as_float(__builtin_amdgcn_readlane(__float_as_int(n0v), 63)); \
            float f2 = __int_as_float(__builtin_amdgcn_readlane(__float_as_int(n1v), 63)); \
            float f3 = __int_as_float(__builtin_amdgcn_readlane(__float_as_int(n2v), 63)); \
            uo0 = uc0; uc0 = fdpp<0x138, 0xF>(NEGV, n0v);                     \
            uo1 = uc1; uc1 = fdpp<0x138, 0xF>(f1, n1v);                       \
            uo2 = uc2; uc2 = fdpp<0x138, 0xF>(f2, n2v);                       \
            uo3 = uc3; uc3 = fdpp<0x138, 0xF>(f3, n3v);                       \
            ++jj0;                                                            \
        }

        #pragma unroll 1
        for (int t4 = 0; t4 < 768; t4 += 4) {
            DTW_STEP(C0) RELOAD(C0, t4 + 4)
            DTW_STEP(C1) RELOAD(C1, t4 + 5)
            DTW_STEP(C2) RELOAD(C2, t4 + 6)
            DTW_STEP(C3) RELOAD(C3, t4 + 7)
        }
#undef DTW_STEP
#undef CELL
#undef RELOAD
        if (lane == 63) out_score[b] = dp33;   // row 1023, col 511 (step 766)
        return;
    }

    // ---------------- PV GEMM path ----------------
    const int bid = blockIdx.x - 16;
    const int n0 = (bid & 3) * 128;          // D/128 = 4
    const int m0 = ((bid >> 2) & 7) * 128;   // A/128 = 8
    const int bz = bid >> 5;                 // 16 batches
    const int K = V_DIM, N = D_DIM;

    const unsigned short* Ab = Pbf + (size_t)bz * A_DIM * V_DIM;
    const unsigned short* Bb = vTb + (size_t)bz * V_DIM * D_DIM;
    float*                Cb = out_aligned + (size_t)bz * A_DIM * D_DIM;

    const int tid = threadIdx.x, lane = tid & 63;
    const int w = tid >> 6, wy = w >> 1, wx = w & 1;
    const int u0 = tid, u1 = tid + 256;
    const int r_u0 = ((u0 >> 6) << 4) + (u0 & 15), k_u0 = ((u0 >> 4) & 3) * 8;
    const int r_u1 = ((u1 >> 6) << 4) + (u1 & 15), k_u1 = ((u1 >> 4) & 3) * 8;

    const unsigned short* gA0 = Ab + (size_t)(m0 + r_u0) * K + k_u0;
    const unsigned short* gA1 = Ab + (size_t)(m0 + r_u1) * K + k_u1;
    const unsigned short* gB0 = Bb + (size_t)(n0 + r_u0) * K + k_u0;
    const unsigned short* gB1 = Bb + (size_t)(n0 + r_u1) * K + k_u1;

    floatx4 acc[4][4];
    #pragma unroll
    for (int i = 0; i < 4; ++i)
        #pragma unroll
        for (int j = 0; j < 4; ++j) acc[i][j] = (floatx4){0.f, 0.f, 0.f, 0.f};

    bf16x8 a0 = *(const bf16x8*)(gA0);
    bf16x8 a1 = *(const bf16x8*)(gA1);
    bf16x8 b0 = *(const bf16x8*)(gB0);
    bf16x8 b1 = *(const bf16x8*)(gB1);

    for (int k0 = 0; k0 < K; k0 += 32) {
        __syncthreads();
        *(bf16x8*)&lA[(size_t)u0 * 8] = a0;
        *(bf16x8*)&lA[(size_t)u1 * 8] = a1;
        *(bf16x8*)&lB[(size_t)u0 * 8] = b0;
        *(bf16x8*)&lB[(size_t)u1 * 8] = b1;
        __syncthreads();
        if (k0 + 32 < K) {
            a0 = *(const bf16x8*)(gA0 + k0 + 32);
            a1 = *(const bf16x8*)(gA1 + k0 + 32);
            b0 = *(const bf16x8*)(gB0 + k0 + 32);
            b1 = *(const bf16x8*)(gB1 + k0 + 32);
        }
        bf16x8 fa[4], fb[4];
        #pragma unroll
        for (int t = 0; t < 4; ++t) {
            fa[t] = *(const bf16x8*)&lA[(((wy*4 + t)*64) + lane) * 8];
            fb[t] = *(const bf16x8*)&lB[(((wx*4 + t)*64) + lane) * 8];
        }
        #pragma unroll
        for (int i = 0; i < 4; ++i)
            #pragma unroll
            for (int j = 0; j < 4; ++j)
                acc[i][j] = __builtin_amdgcn_mfma_f32_16x16x32_bf16(fa[i], fb[j], acc[i][j], 0, 0, 0);
    }

    const int q = lane >> 4, c = lane & 15;
    #pragma unroll
    for (int i = 0; i < 4; ++i)
        #pragma unroll
        for (int j = 0; j < 4; ++j) {
            const int n = n0 + (wx*4 + j)*16 + c;
            #pragma unroll
            for (int r = 0; r < 4; ++r) {
                const int m = m0 + (wy*4 + i)*16 + q*4 + r;
                Cb[(size_t)m * N + n] = acc[i][j][r];
            }
        }
}

// ---------------------------------------------------------------------------
extern "C" void kernel_launch(void* const* d_in, const int* in_sizes, int n_in,
                              void* d_out, int out_size, void* d_ws, size_t ws_size,
                              hipStream_t stream)
{
    const float* audio = (const float*)d_in[0];   // [16,1024,512]
    const float* video = (const float*)d_in[1];   // [16, 512,512]
    const float* W     = (const float*)d_in[2];   // [512,512]
    const float* bias  = (const float*)d_in[3];   // [512]

    float* out_aligned = (float*)d_out;
    float* out_score   = (float*)d_out + (size_t)B_DIM * A_DIM * D_DIM;

    const size_t NA = (size_t)B_DIM * A_DIM * D_DIM;   // 8.39M
    const size_t NV = (size_t)B_DIM * V_DIM * D_DIM;   // 4.19M
    const size_t NS = (size_t)B_DIM * A_DIM * V_DIM;   // 8.39M

    float* ws = (float*)d_ws;
    float*          a_p  = ws;                                 // NA fp32 [dead after rownorm-a]
    float*          v_p  = a_p + NA;                           // NV fp32
    float*          sim  = v_p + NV;                           // NS fp32
    unsigned short* abf  = (unsigned short*)(sim + NS);        // NA bf16 [dead after proj-a]
    unsigned short* vbf  = (unsigned short*)(sim + NS) + NA;   // NV bf16 [dead after proj-v]
    unsigned short* v_nb = vbf + NV;                           // NV bf16
    unsigned short* Wbf  = v_nb + NV;                          // 262144 bf16
    unsigned short* a_nb = (unsigned short*)v_p;               // NA bf16 reuses v_p
    unsigned short* Pbf  = abf;                                // NS bf16 reuses dead abf
    unsigned short* vTb  = vbf;                                // NV bf16 reuses dead vbf
    // skewT: 16 x 768 x 1024 fp32 = 12.58M floats — exactly overlays
    // a_p (8.39M) + v_p (4.19M), both dead when softmax_skewT writes it.
    float*          skewT = a_p;

    // 1) fp32 -> bf16 input conversions, one merged launch
    {
        const int nb_a = (int)(NA / 8 / 256);             // 4096
        const int nb_v = (int)(NV / 8 / 256);             // 2048
        const int nb_w = D_DIM * D_DIM / 8 / 256;         // 128
        cvt3_bf16_kernel<<<dim3(nb_a + nb_v + nb_w), dim3(256), 0, stream>>>(
            audio, abf, nb_a, video, vbf, nb_v, W, Wbf);
    }

    // 2) projections: X @ W^T + b
    gemm_bf16_nt<<<dim3(D_DIM/128, (B_DIM*A_DIM)/128, 1), dim3(256), 0, stream>>>(
        abf, Wbf, bias, a_p, B_DIM*A_DIM, D_DIM, D_DIM, 0, 0, 0);
    gemm_bf16_nt<<<dim3(D_DIM/128, (B_DIM*V_DIM)/128, 1), dim3(256), 0, stream>>>(
        vbf, Wbf, bias, v_p, B_DIM*V_DIM, D_DIM, D_DIM, 0, 0, 0);

    // 3) normalize -> bf16 (v first: frees v_p for a_nb)
    rownorm_cvt_kernel<<<dim3((B_DIM*V_DIM)/4), dim3(256), 0, stream>>>(v_p, v_nb);
    rownorm_cvt_kernel<<<dim3((B_DIM*A_DIM)/4), dim3(256), 0, stream>>>(a_p, a_nb);

    // 4) sim[b] = a_n[b] @ v_n[b]^T
    gemm_bf16_nt<<<dim3(V_DIM/128, A_DIM/128, B_DIM), dim3(256), 0, stream>>>(
        a_nb, v_nb, nullptr, sim, A_DIM, V_DIM, D_DIM,
        (size_t)A_DIM*D_DIM, (size_t)V_DIM*D_DIM, (size_t)A_DIM*V_DIM);

    // 5) video -> vT bf16 (independent of sim)
    transpose_cvt_kernel<<<dim3(D_DIM/32, V_DIM/32, B_DIM), dim3(256), 0, stream>>>(video, vTb);

    // 6) fused row softmax -> Pbf + transposed skewed sim copy for DTW
    softmax_skewT_kernel<<<dim3((B_DIM*A_DIM)/4), dim3(256), 0, stream>>>(sim, Pbf, skewT);

    // 7) fused PV GEMM + 1-wave coalesced-column DTW
    pv_dtw_kernel<<<dim3(16 + (D_DIM/128)*(A_DIM/128)*B_DIM), dim3(256), 0, stream>>>(
        Pbf, vTb, skewT, out_aligned, out_score);
}

// Round 8
// 284.460 us; speedup vs baseline: 1.3177x; 1.3177x over previous
//
#include <hip/hip_runtime.h>
#include <math.h>

#define B_DIM 16
#define A_DIM 1024
#define V_DIM 512
#define D_DIM 512
#define NEGV  (-1e30f)
#define SKT_W 768   // skewT phys columns; pc = (c + off) mod 768, wrap-safe

typedef short bf16x8 __attribute__((ext_vector_type(8)));
typedef float floatx4 __attribute__((ext_vector_type(4)));

// round-to-nearest-even fp32 -> bf16
__device__ __forceinline__ short bf16_rne(float f) {
    unsigned u = __float_as_uint(f);
    return (short)((u + 0x7fffu + ((u >> 16) & 1u)) >> 16);
}

__device__ __forceinline__ float max3f(float a, float b, float c) {
    float d;
    asm("v_max3_f32 %0, %1, %2, %3" : "=v"(d) : "v"(a), "v"(b), "v"(c));
    return d;
}

// ---------------------------------------------------------------------------
// Merged elementwise fp32 -> bf16 for three segments (8 elems/thread).
// ---------------------------------------------------------------------------
__global__ __launch_bounds__(256) void cvt3_bf16_kernel(
    const float* __restrict__ in0, unsigned short* __restrict__ out0, int nb0,
    const float* __restrict__ in1, unsigned short* __restrict__ out1, int nb1,
    const float* __restrict__ in2, unsigned short* __restrict__ out2)
{
    int blk = blockIdx.x;
    const float* in; unsigned short* out;
    if (blk < nb0)              { in = in0; out = out0; }
    else if (blk < nb0 + nb1)   { in = in1; out = out1; blk -= nb0; }
    else                        { in = in2; out = out2; blk -= nb0 + nb1; }
    const int i = blk * 256 + threadIdx.x;
    float4 u = ((const float4*)in)[2*i];
    float4 v = ((const float4*)in)[2*i + 1];
    bf16x8 h;
    h[0]=bf16_rne(u.x); h[1]=bf16_rne(u.y); h[2]=bf16_rne(u.z); h[3]=bf16_rne(u.w);
    h[4]=bf16_rne(v.x); h[5]=bf16_rne(v.y); h[6]=bf16_rne(v.z); h[7]=bf16_rne(v.w);
    *(bf16x8*)(out + (size_t)i * 8) = h;
}

// ---------------------------------------------------------------------------
// bf16 MFMA NT GEMM tile body (128x128, BK=32, reg-prefetch K-pipeline).
// Mechanical extraction of the verified gemm_bf16_nt body.
// ---------------------------------------------------------------------------
__device__ __forceinline__ void gemm_tile_body(
    const unsigned short* __restrict__ Ab, const unsigned short* __restrict__ Bb,
    const float* __restrict__ bias, float* __restrict__ Cb,
    int m0, int n0, int K, int N,
    unsigned short* lA, unsigned short* lB)
{
    const int tid = threadIdx.x, lane = tid & 63;
    const int w = tid >> 6, wy = w >> 1, wx = w & 1;

    const int u0 = tid, u1 = tid + 256;
    const int r_u0 = ((u0 >> 6) << 4) + (u0 & 15), k_u0 = ((u0 >> 4) & 3) * 8;
    const int r_u1 = ((u1 >> 6) << 4) + (u1 & 15), k_u1 = ((u1 >> 4) & 3) * 8;

    const unsigned short* gA0 = Ab + (size_t)(m0 + r_u0) * K + k_u0;
    const unsigned short* gA1 = Ab + (size_t)(m0 + r_u1) * K + k_u1;
    const unsigned short* gB0 = Bb + (size_t)(n0 + r_u0) * K + k_u0;
    const unsigned short* gB1 = Bb + (size_t)(n0 + r_u1) * K + k_u1;

    floatx4 acc[4][4];
    #pragma unroll
    for (int i = 0; i < 4; ++i)
        #pragma unroll
        for (int j = 0; j < 4; ++j) acc[i][j] = (floatx4){0.f, 0.f, 0.f, 0.f};

    bf16x8 a0 = *(const bf16x8*)(gA0);
    bf16x8 a1 = *(const bf16x8*)(gA1);
    bf16x8 b0 = *(const bf16x8*)(gB0);
    bf16x8 b1 = *(const bf16x8*)(gB1);

    for (int k0 = 0; k0 < K; k0 += 32) {
        __syncthreads();
        *(bf16x8*)&lA[(size_t)u0 * 8] = a0;
        *(bf16x8*)&lA[(size_t)u1 * 8] = a1;
        *(bf16x8*)&lB[(size_t)u0 * 8] = b0;
        *(bf16x8*)&lB[(size_t)u1 * 8] = b1;
        __syncthreads();

        if (k0 + 32 < K) {
            a0 = *(const bf16x8*)(gA0 + k0 + 32);
            a1 = *(const bf16x8*)(gA1 + k0 + 32);
            b0 = *(const bf16x8*)(gB0 + k0 + 32);
            b1 = *(const bf16x8*)(gB1 + k0 + 32);
        }

        bf16x8 fa[4], fb[4];
        #pragma unroll
        for (int t = 0; t < 4; ++t) {
            fa[t] = *(const bf16x8*)&lA[(((wy*4 + t)*64) + lane) * 8];
            fb[t] = *(const bf16x8*)&lB[(((wx*4 + t)*64) + lane) * 8];
        }
        #pragma unroll
        for (int i = 0; i < 4; ++i)
            #pragma unroll
            for (int j = 0; j < 4; ++j)
                acc[i][j] = __builtin_amdgcn_mfma_f32_16x16x32_bf16(fa[i], fb[j], acc[i][j], 0, 0, 0);
    }

    const int q = lane >> 4, c = lane & 15;
    #pragma unroll
    for (int i = 0; i < 4; ++i)
        #pragma unroll
        for (int j = 0; j < 4; ++j) {
            const int n = n0 + (wx*4 + j)*16 + c;
            const float bv = bias ? bias[n] : 0.f;
            #pragma unroll
            for (int r = 0; r < 4; ++r) {
                const int m = m0 + (wy*4 + i)*16 + q*4 + r;
                Cb[(size_t)m * N + n] = acc[i][j][r] + bv;
            }
        }
}

// sim GEMM (batched NT): unchanged semantics.
__global__ __launch_bounds__(256) void gemm_bf16_nt(
    const unsigned short* __restrict__ Ag, const unsigned short* __restrict__ Bg,
    const float* __restrict__ bias, float* __restrict__ Cg,
    int M, int N, int K, size_t strA, size_t strB, size_t strC)
{
    __shared__ __align__(16) unsigned short lA[8*64*8];
    __shared__ __align__(16) unsigned short lB[8*64*8];
    const unsigned short* Ab = Ag + (size_t)blockIdx.z * strA;
    const unsigned short* Bb = Bg + (size_t)blockIdx.z * strB;
    float*                Cb = Cg + (size_t)blockIdx.z * strC;
    gemm_tile_body(Ab, Bb, bias, Cb, blockIdx.y * 128, blockIdx.x * 128, K, N, lA, lB);
}

// Merged projections: audio (by<128) and video (by>=128) in one launch.
__global__ __launch_bounds__(256) void gemm_proj2(
    const unsigned short* __restrict__ abf, const unsigned short* __restrict__ vbf,
    const unsigned short* __restrict__ Wbf, const float* __restrict__ bias,
    float* __restrict__ a_p, float* __restrict__ v_p)
{
    __shared__ __align__(16) unsigned short lA[8*64*8];
    __shared__ __align__(16) unsigned short lB[8*64*8];
    const int by = blockIdx.y;
    const unsigned short* Ab; float* Cb; int m0;
    if (by < 128) { Ab = abf; Cb = a_p; m0 = by * 128; }
    else          { Ab = vbf; Cb = v_p; m0 = (by - 128) * 128; }
    gemm_tile_body(Ab, Wbf, bias, Cb, m0, blockIdx.x * 128, D_DIM, D_DIM, lA, lB);
}

// ---------------------------------------------------------------------------
// Merged: rownorm-a (blocks 0..4095, a_p->a_nb), rownorm-v (4096..6143,
// v_p->v_nb), 32x32 transpose+cvt video->vT bf16 (6144..10239).
// All segments touch disjoint memory (a_nb lives in dead abf region).
// ---------------------------------------------------------------------------
__global__ __launch_bounds__(256) void norm2_transpose_kernel(
    const float* __restrict__ a_p, unsigned short* __restrict__ a_nb,
    const float* __restrict__ v_p, unsigned short* __restrict__ v_nb,
    const float* __restrict__ video, unsigned short* __restrict__ vTb)
{
    __shared__ float t[32][33];
    const int bx = blockIdx.x;
    if (bx < 6144) {
        const float* in; unsigned short* out; int rb;
        if (bx < 4096) { in = a_p; out = a_nb; rb = bx; }
        else           { in = v_p; out = v_nb; rb = bx - 4096; }
        const int wave = threadIdx.x >> 6;
        const int lane = threadIdx.x & 63;
        const size_t r = (size_t)rb * 4 + wave;
        const float* p = in + r * D_DIM + lane * 8;
        float4 u = *(const float4*)p;
        float4 w = *(const float4*)(p + 4);
        float ss = u.x*u.x + u.y*u.y + u.z*u.z + u.w*u.w
                 + w.x*w.x + w.y*w.y + w.z*w.z + w.w*w.w;
        #pragma unroll
        for (int m = 1; m < 64; m <<= 1) ss += __shfl_xor(ss, m, 64);
        const float inv = 1.0f / fmaxf(sqrtf(ss), 1e-12f);
        bf16x8 h;
        h[0]=bf16_rne(u.x*inv); h[1]=bf16_rne(u.y*inv); h[2]=bf16_rne(u.z*inv); h[3]=bf16_rne(u.w*inv);
        h[4]=bf16_rne(w.x*inv); h[5]=bf16_rne(w.y*inv); h[6]=bf16_rne(w.z*inv); h[7]=bf16_rne(w.w*inv);
        *(bf16x8*)(out + r * D_DIM + lane * 8) = h;
    } else {
        const int tt = bx - 6144;
        const int d0 = (tt & 15) * 32;
        const int v0 = ((tt >> 4) & 15) * 32;
        const int b  = tt >> 8;
        const int x = threadIdx.x & 31, y0 = (threadIdx.x >> 5) * 4;
        const float* I = video + ((size_t)b * V_DIM + v0) * D_DIM + d0;
        #pragma unroll
        for (int r = 0; r < 4; ++r) t[y0 + r][x] = I[(size_t)(y0 + r) * D_DIM + x];
        __syncthreads();
        unsigned short* O = vTb + ((size_t)b * D_DIM + d0) * V_DIM + v0;
        #pragma unroll
        for (int r = 0; r < 4; ++r) O[(size_t)(y0 + r) * V_DIM + x] = (unsigned short)bf16_rne(t[x][y0 + r]);
    }
}

// ---------------------------------------------------------------------------
// DPP helper (wave64). 0x138 = wave_shr:1 (lane l <- l-1; lane 0 keeps oldv
// with bound_ctrl=false). Verified in prior rounds.
// ---------------------------------------------------------------------------
template <int CTRL, int RMASK>
__device__ __forceinline__ float fdpp(float oldv, float src) {
    int r = __builtin_amdgcn_update_dpp(
        __float_as_int(oldv), __float_as_int(src), CTRL, RMASK, 0xF, false);
    return __int_as_float(r);
}

// ---------------------------------------------------------------------------
// Fused: row softmax -> Pbf (bf16) + COLUMN-MAJOR skewed fp32 sim copy:
// skewT[b][(c + off) % 768][i] = sim[b][i][c], off(i) = ((i>>2)&63) + 72*(i>>8)
// (= R5 systolic lane/wave offsets: quad g = i>>2 owned by lane g&63 of wave
// g>>6). All 4 rows of a block form one quad -> same off -> contiguous 16B
// runs via LDS transpose. Mod-768 wrap is collision-free (c unique per slot)
// and the DTW reader's jj<512 guard selects exactly the valid columns.
// ---------------------------------------------------------------------------
__global__ __launch_bounds__(256) void softmax_skewT_kernel(
    const float* __restrict__ sim, unsigned short* __restrict__ Pbf,
    float* __restrict__ skewT)
{
    __shared__ float tl[4][520];
    const int wave = threadIdx.x >> 6;
    const int lane = threadIdx.x & 63;
    const size_t r = (size_t)blockIdx.x * 4 + wave;
    const float* p = sim + r * V_DIM + lane * 8;
    float4 u = *(const float4*)p;
    float4 w = *(const float4*)(p + 4);
    float s[8] = {u.x,u.y,u.z,u.w,w.x,w.y,w.z,w.w};

    float m = s[0];
    #pragma unroll
    for (int k = 1; k < 8; ++k) m = fmaxf(m, s[k]);
    #pragma unroll
    for (int t = 1; t < 64; t <<= 1) m = fmaxf(m, __shfl_xor(m, t, 64));

    const float L2E = 1.44269504f;
    float ex[8];
    float e = 0.f;
    #pragma unroll
    for (int k = 0; k < 8; ++k) { ex[k] = exp2f((s[k] - m) * L2E); e += ex[k]; }
    #pragma unroll
    for (int t = 1; t < 64; t <<= 1) e += __shfl_xor(e, t, 64);
    const float ri = 1.0f / e;

    bf16x8 h;
    #pragma unroll
    for (int k = 0; k < 8; ++k) h[k] = bf16_rne(ex[k] * ri);
    *(bf16x8*)(Pbf + r * V_DIM + lane * 8) = h;

    // stash raw sim rows in LDS, write transposed 16B runs
    #pragma unroll
    for (int k = 0; k < 8; ++k) tl[wave][lane * 8 + k] = s[k];
    __syncthreads();

    const int r0 = blockIdx.x * 4;
    const int b  = r0 >> 10;
    const int i0 = r0 & 1023;
    const int g  = i0 >> 2;
    const int off = (g & 63) + 72 * (g >> 6);
    float* sbase = skewT + (size_t)b * SKT_W * 1024 + i0;
    #pragma unroll
    for (int cc = 0; cc < 2; ++cc) {
        const int c = threadIdx.x + cc * 256;
        int pc = c + off; if (pc >= SKT_W) pc -= SKT_W;
        float4 v = make_float4(tl[0][c], tl[1][c], tl[2][c], tl[3][c]);
        *(float4*)(sbase + (size_t)pc * 1024) = v;
    }
}

// ---------------------------------------------------------------------------
// Fused PV GEMM + 256-lane batched-barrier wavefront DTW with COALESCED
// column loads. Structure = R5 (verified): lane g owns rows 4g..4g+3,
// off = (g&63) + 72*(g>>6); barrier once per 8-step batch; boundary rows via
// per-wave 520-slot LDS arrays (write-once slots, NEG prefill, dump slot).
// New vs R5: c-values come from column-major skewT — one float4 per lane per
// step, per-wave contiguous 1KB loads (16 lines vs 64 uncoalesced).
// ---------------------------------------------------------------------------
__global__ __launch_bounds__(256) void pv_dtw_kernel(
    const unsigned short* __restrict__ Pbf, const unsigned short* __restrict__ vTb,
    const float* __restrict__ skewT, float* __restrict__ out_aligned,
    float* __restrict__ out_score)
{
    __shared__ __align__(16) unsigned short lA[8*64*8];
    __shared__ __align__(16) unsigned short lB[8*64*8];

    if (blockIdx.x < 16) {
        // ---------------- DTW path (all 256 threads) ----------------
        const int b    = blockIdx.x;
        const int tid  = threadIdx.x;
        const int lane = tid & 63;
        const int wv   = tid >> 6;
        const int off  = lane + 72 * wv;

        float* bndAll = (float*)lA;                    // 3 x 520 floats
        float* bndP = bndAll + wv * 520;
        const float* bndC = bndAll + (wv > 0 ? wv - 1 : 0) * 520;
        for (int i = tid; i < 3 * 520; i += 256) bndAll[i] = NEGV;
        __syncthreads();

        const float* Sb = skewT + (size_t)b * SKT_W * 1024 + 4 * tid;

        float dp[4] = {NEGV, NEGV, NEGV, NEGV};
        float st[8];
        float upC = NEGV;
        float upL = (tid == 0) ? 0.0f : NEGV;

        float4 CA[8], CB[8];
        #pragma unroll
        for (int k = 0; k < 8; ++k) CA[k] = *(const float4*)(Sb + (size_t)k * 1024);
        #pragma unroll
        for (int k = 0; k < 8; ++k) CB[k] = *(const float4*)(Sb + (size_t)(k + 8) * 1024);

// one systolic step (K compile-time; CK = float4 of this lane's 4 rows at
// column sb+K). FK = fill for step sb+K+1. Cell math = R5-verified.
#define DTW_STEP(K, CK, FK)                                                   \
        {                                                                     \
            const unsigned jj = (unsigned)(sb + (K) - off);                   \
            if (jj < 512u) {                                                  \
                float u = upC, g = upL, old, nd;                              \
                old = dp[0]; nd = (CK).x + max3f(u, dp[0], g); dp[0] = nd; g = old; u = nd; \
                old = dp[1]; nd = (CK).y + max3f(u, dp[1], g); dp[1] = nd; g = old; u = nd; \
                old = dp[2]; nd = (CK).z + max3f(u, dp[2], g); dp[2] = nd; g = old; u = nd; \
                old = dp[3]; nd = (CK).w + max3f(u, dp[3], g); dp[3] = nd;                  \
            }                                                                 \
            st[K] = dp[3];                                                    \
            upL = upC;                                                        \
            upC = fdpp<0x138, 0xF>((FK), dp[3]);                              \
        }

// one 8-step batch on buffer CC, refill CC <- columns sb+16..sb+23, barrier.
#define DTW_BATCH(CC)                                                         \
        {                                                                     \
            float4 f0, f1;                                                    \
            const int ps = sb + 8 - 72 * wv;                                  \
            if (wv > 0 && ps >= 0 && ps <= 512) {                             \
                f0 = *(const float4*)&bndC[ps];                               \
                f1 = *(const float4*)&bndC[ps + 4];                           \
            } else {                                                          \
                f0 = make_float4(NEGV, NEGV, NEGV, NEGV); f1 = f0;            \
            }                                                                 \
            DTW_STEP(0, CC[0], f0.x) DTW_STEP(1, CC[1], f0.y)                 \
            DTW_STEP(2, CC[2], f0.z) DTW_STEP(3, CC[3], f0.w)                 \
            DTW_STEP(4, CC[4], f1.x) DTW_STEP(5, CC[5], f1.y)                 \
            DTW_STEP(6, CC[6], f1.z) DTW_STEP(7, CC[7], f1.w)                 \
            {                                                                 \
                _Pragma("unroll")                                             \
                for (int k = 0; k < 8; ++k) {                                 \
                    int cc_ = sb + 16 + k; if (cc_ >= SKT_W) cc_ -= SKT_W;    \
                    CC[k] = *(const float4*)(Sb + (size_t)cc_ * 1024);        \
                }                                                             \
            }                                                                 \
            if (wv < 3 && lane == 63) {                                       \
                _Pragma("unroll")                                             \
                for (int k = 0; k < 8; ++k) {                                 \
                    const int jp = sb + k - 63 - 72 * wv;                     \
                    const int adr = ((unsigned)jp < 512u) ? (jp + 7) : 519;   \
                    bndP[adr] = st[k];                                        \
                }                                                             \
            }                                                                 \
            asm volatile("s_waitcnt lgkmcnt(0)" ::: "memory");                \
            __builtin_amdgcn_s_barrier();                                     \
            asm volatile("" ::: "memory");                                    \
        }

        #pragma unroll 1
        for (int bt = 0; bt < 100; bt += 2) {
            int sb = bt * 8;
            DTW_BATCH(CA)
            sb += 8;
            DTW_BATCH(CB)
        }
#undef DTW_BATCH
#undef DTW_STEP
        if (tid == 255) out_score[b] = dp[3];   // row 1023, col 511 (t=790)
        return;
    }

    // ---------------- PV GEMM path ----------------
    const int bid = blockIdx.x - 16;
    const int n0 = (bid & 3) * 128;          // D/128 = 4
    const int m0 = ((bid >> 2) & 7) * 128;   // A/128 = 8
    const int bz = bid >> 5;                 // 16 batches

    const unsigned short* Ab = Pbf + (size_t)bz * A_DIM * V_DIM;
    const unsigned short* Bb = vTb + (size_t)bz * V_DIM * D_DIM;
    float*                Cb = out_aligned + (size_t)bz * A_DIM * D_DIM;

    gemm_tile_body(Ab, Bb, nullptr, Cb, m0, n0, V_DIM, D_DIM, lA, lB);
}

// ---------------------------------------------------------------------------
extern "C" void kernel_launch(void* const* d_in, const int* in_sizes, int n_in,
                              void* d_out, int out_size, void* d_ws, size_t ws_size,
                              hipStream_t stream)
{
    const float* audio = (const float*)d_in[0];   // [16,1024,512]
    const float* video = (const float*)d_in[1];   // [16, 512,512]
    const float* W     = (const float*)d_in[2];   // [512,512]
    const float* bias  = (const float*)d_in[3];   // [512]

    float* out_aligned = (float*)d_out;
    float* out_score   = (float*)d_out + (size_t)B_DIM * A_DIM * D_DIM;

    const size_t NA = (size_t)B_DIM * A_DIM * D_DIM;   // 8.39M
    const size_t NV = (size_t)B_DIM * V_DIM * D_DIM;   // 4.19M
    const size_t NS = (size_t)B_DIM * A_DIM * V_DIM;   // 8.39M

    float* ws = (float*)d_ws;
    float*          a_p  = ws;                                 // NA fp32 [dead after norm-a]
    float*          v_p  = a_p + NA;                           // NV fp32 [dead after norm-v]
    float*          sim  = v_p + NV;                           // NS fp32
    unsigned short* abf  = (unsigned short*)(sim + NS);        // NA bf16 [dead after proj-a]
    unsigned short* vbf  = (unsigned short*)(sim + NS) + NA;   // NV bf16 [dead after proj-v]
    unsigned short* v_nb = vbf + NV;                           // NV bf16
    unsigned short* Wbf  = v_nb + NV;                          // 262144 bf16
    unsigned short* a_nb = abf;            // NA bf16 reuses dead abf (norm-a)
    unsigned short* Pbf  = abf;            // NS bf16 reuses a_nb (dead after sim GEMM)
    unsigned short* vTb  = vbf;            // NV bf16 reuses dead vbf
    // skewT: 16 x 768 x 1024 fp32 = 12.58M floats = a_p + v_p exactly.
    float*          skewT = a_p;

    // 1) fp32 -> bf16 input conversions, one merged launch
    {
        const int nb_a = (int)(NA / 8 / 256);             // 4096
        const int nb_v = (int)(NV / 8 / 256);             // 2048
        const int nb_w = D_DIM * D_DIM / 8 / 256;         // 128
        cvt3_bf16_kernel<<<dim3(nb_a + nb_v + nb_w), dim3(256), 0, stream>>>(
            audio, abf, nb_a, video, vbf, nb_v, W, Wbf);
    }

    // 2) merged projections: audio & video X @ W^T + b
    gemm_proj2<<<dim3(D_DIM/128, 192), dim3(256), 0, stream>>>(
        abf, vbf, Wbf, bias, a_p, v_p);

    // 3) merged rownorm-a + rownorm-v + video transpose
    norm2_transpose_kernel<<<dim3(4096 + 2048 + 4096), dim3(256), 0, stream>>>(
        a_p, a_nb, v_p, v_nb, video, vTb);

    // 4) sim[b] = a_n[b] @ v_n[b]^T
    gemm_bf16_nt<<<dim3(V_DIM/128, A_DIM/128, B_DIM), dim3(256), 0, stream>>>(
        a_nb, v_nb, nullptr, sim, A_DIM, V_DIM, D_DIM,
        (size_t)A_DIM*D_DIM, (size_t)V_DIM*D_DIM, (size_t)A_DIM*V_DIM);

    // 5) fused row softmax -> Pbf + column-major skewed sim copy for DTW
    softmax_skewT_kernel<<<dim3((B_DIM*A_DIM)/4), dim3(256), 0, stream>>>(sim, Pbf, skewT);

    // 6) fused PV GEMM + 4-wave batched coalesced DTW
    pv_dtw_kernel<<<dim3(16 + (D_DIM/128)*(A_DIM/128)*B_DIM), dim3(256), 0, stream>>>(
        Pbf, vTb, skewT, out_aligned, out_score);
}